// Round 23
// baseline (97.952 us; speedup 1.0000x reference)
//
#include <hip/hip_runtime.h>
#include <hip/hip_bf16.h>
#include <math.h>

#define NB   2
#define CIN  64
#define CENC 96
#define DK   64
#define DV   64
#define LL   9216
#define QBLK 256
#define KVBLK 64
#define NQT  (LL/QBLK)          // 36
#define LOG2E 1.44269504088896340736f

typedef __attribute__((ext_vector_type(8)))  short short8;
typedef __attribute__((ext_vector_type(16))) float f32x16;
typedef __attribute__((ext_vector_type(2)))  unsigned int uint2v;
typedef unsigned int uint;

__device__ inline void gload16(const void* g, void* l) {
    __builtin_amdgcn_global_load_lds(
        (const __attribute__((address_space(1))) unsigned int*)g,
        (__attribute__((address_space(3))) unsigned int*)l, 16, 0, 0);
}

__device__ inline unsigned short f2bf(float f) {
    union { float f; uint u; } v; v.f = f;
    uint r = (v.u + 0x7FFFu + ((v.u >> 16) & 1u)) >> 16;
    return (unsigned short)r;
}

__device__ inline float bf2f(uint u) {
    union { uint u; float f; } c; c.u = u << 16; return c.f;
}

// single-instruction packed f32->bf16 (RNE)
__device__ inline uint cvtpk(float lo, float hi) {
    uint r;
    asm("v_cvt_pk_bf16_f32 %0, %1, %2" : "=v"(r) : "v"(lo), "v"(hi));
    return r;
}

// exchange a[32:63] <-> b[0:31]
__device__ inline void plswap(uint& a, uint& b) {
#if __has_builtin(__builtin_amdgcn_permlane32_swap)
    uint2v r = __builtin_amdgcn_permlane32_swap(a, b, false, false);
    a = r.x; b = r.y;
#else
    const int lane = threadIdx.x & 63;
    uint t = (lane < 32) ? b : a;
    t = __shfl_xor(t, 32, 64);
    uint an = (lane < 32) ? a : t;
    uint bn = (lane < 32) ? t : b;
    a = an; b = bn;
#endif
}

// ---------------- fused projections (float4 x-loads) ----------------
__global__ __launch_bounds__(256) void proj_kernel(
    const float* __restrict__ x, const float* __restrict__ x_enc,
    const float* __restrict__ Wq, const float* __restrict__ bq,
    const float* __restrict__ Wk, const float* __restrict__ bk,
    const float* __restrict__ Wv, const float* __restrict__ bv,
    unsigned short* __restrict__ Qb, unsigned short* __restrict__ Kb,
    unsigned short* __restrict__ Vt, int nqk)
{
    __shared__ float sh[2 * CENC * 64];   // 48KB
    const int tid = threadIdx.x;

    if ((int)blockIdx.x < nqk) {
        float* Wt0 = sh;
        float* Wt1 = sh + CENC * 64;
        for (int idx = tid; idx < DK * CENC; idx += 256) {
            int k = idx / CENC, c = idx - k * CENC;
            Wt0[c * 64 + (k ^ (c & 31))] = Wq[idx];
            Wt1[c * 64 + (k ^ (c & 31))] = Wk[idx];
        }
        __syncthreads();

        const int w    = __builtin_amdgcn_readfirstlane(tid >> 6);
        const int lane = tid & 63;
        const int gw   = blockIdx.x * 4 + w;
        const int p0g  = gw * 16;
        const int b    = p0g / LL;
        const int p0   = p0g - b * LL;

        float qa[16], ka[16];
        const float bqv = bq[lane], bkv = bk[lane];
#pragma unroll
        for (int p = 0; p < 16; ++p) { qa[p] = bqv; ka[p] = bkv; }

        const float* xp = x_enc + (size_t)b * CENC * LL + p0;
#pragma unroll 4
        for (int c = 0; c < CENC; ++c) {
            const float wq = Wt0[c * 64 + (lane ^ (c & 31))];
            const float wk = Wt1[c * 64 + (lane ^ (c & 31))];
            const float4* xc4 = (const float4*)(xp + (size_t)c * LL);
#pragma unroll
            for (int p4 = 0; p4 < 4; ++p4) {
                const float4 xv = xc4[p4];
                qa[4 * p4 + 0] = fmaf(wq, xv.x, qa[4 * p4 + 0]);
                qa[4 * p4 + 1] = fmaf(wq, xv.y, qa[4 * p4 + 1]);
                qa[4 * p4 + 2] = fmaf(wq, xv.z, qa[4 * p4 + 2]);
                qa[4 * p4 + 3] = fmaf(wq, xv.w, qa[4 * p4 + 3]);
                ka[4 * p4 + 0] = fmaf(wk, xv.x, ka[4 * p4 + 0]);
                ka[4 * p4 + 1] = fmaf(wk, xv.y, ka[4 * p4 + 1]);
                ka[4 * p4 + 2] = fmaf(wk, xv.z, ka[4 * p4 + 2]);
                ka[4 * p4 + 3] = fmaf(wk, xv.w, ka[4 * p4 + 3]);
            }
        }

        unsigned short* qrow = Qb + (size_t)(b * LL + p0) * 64 + lane;
        unsigned short* krow = Kb + (size_t)(b * LL + p0) * 64 + lane;
#pragma unroll
        for (int p = 0; p < 16; ++p) {
            float sq = qa[p] * qa[p];
            float sk = ka[p] * ka[p];
#pragma unroll
            for (int m = 1; m < 64; m <<= 1) {
                sq += __shfl_xor(sq, m, 64);
                sk += __shfl_xor(sk, m, 64);
            }
            qrow[(size_t)p * 64] = f2bf(qa[p] * (LOG2E / fmaxf(sqrtf(sq), 1e-6f)));
            krow[(size_t)p * 64] = f2bf(ka[p] * (1.f / fmaxf(sqrtf(sk), 1e-6f)));
        }
    } else {
        float* Wt = sh;                                        // 16KB
        unsigned short* Vsh = (unsigned short*)(sh + CIN * 64); // 8KB
        for (int idx = tid; idx < DV * CIN; idx += 256) {
            int v = idx / CIN, c = idx - v * CIN;
            Wt[c * 64 + (v ^ (c & 31))] = Wv[idx];
        }
        __syncthreads();

        const int w    = __builtin_amdgcn_readfirstlane(tid >> 6);
        const int lane = tid & 63;
        const int l0g  = ((int)blockIdx.x - nqk) * 64;
        const int b    = l0g / LL;
        const int l0   = l0g - b * LL;
        const int p0   = w * 16;

        float va[16];
        const float bvv = bv[lane];
#pragma unroll
        for (int p = 0; p < 16; ++p) va[p] = bvv;

        const float* xp = x + (size_t)b * CIN * LL + l0 + p0;
#pragma unroll 4
        for (int c = 0; c < CIN; ++c) {
            const float wv = Wt[c * 64 + (lane ^ (c & 31))];
            const float4* xc4 = (const float4*)(xp + (size_t)c * LL);
#pragma unroll
            for (int p4 = 0; p4 < 4; ++p4) {
                const float4 xv = xc4[p4];
                va[4 * p4 + 0] = fmaf(wv, xv.x, va[4 * p4 + 0]);
                va[4 * p4 + 1] = fmaf(wv, xv.y, va[4 * p4 + 1]);
                va[4 * p4 + 2] = fmaf(wv, xv.z, va[4 * p4 + 2]);
                va[4 * p4 + 3] = fmaf(wv, xv.w, va[4 * p4 + 3]);
            }
        }
#pragma unroll
        for (int p = 0; p < 16; ++p) Vsh[(p0 + p) * 64 + lane] = f2bf(va[p]);
        __syncthreads();

        const int v = tid & 63, w2 = tid >> 6;
        uint pk[8];
#pragma unroll
        for (int j = 0; j < 8; ++j)
            pk[j] = (uint)Vsh[(w2 * 16 + 2 * j) * 64 + v] |
                    ((uint)Vsh[(w2 * 16 + 2 * j + 1) * 64 + v] << 16);
        uint4* dst = (uint4*)(Vt + (size_t)b * 64 * LL + (size_t)v * LL + l0 + w2 * 16);
        dst[0] = make_uint4(pk[0], pk[1], pk[2], pk[3]);
        dst[1] = make_uint4(pk[4], pk[5], pk[6], pk[7]);
    }
}

// ---------------- MFMA flash attention: 8 waves x 32q, 4 waves/SIMD (R17-proven) ----------------
__global__ __launch_bounds__(512, 4) void flash_kernel(
    const unsigned short* __restrict__ Qb,
    const unsigned short* __restrict__ Kb,
    const unsigned short* __restrict__ Vt,
    float* __restrict__ Sp, unsigned short* __restrict__ Rp,
    int JS, int nt)
{
    // LDS bytes: K buf0 @0, K buf1 @8192, V buf0 @16384, V buf1 @24576
    __shared__ unsigned short Sh[16384];

    // XCD-aware bijective swizzle (grid divisible by 8)
    const int bid0  = blockIdx.x;
    const int chunk = gridDim.x >> 3;
    const int bid   = (bid0 & 7) * chunk + (bid0 >> 3);

    const int qt  = bid % NQT;
    const int js  = (bid / NQT) % JS;
    const int b   = bid / (NQT * JS);
    const int tid = threadIdx.x;
    const int w = tid >> 6, lane = tid & 63;
    const int ln = lane & 31, h = lane >> 5;
    const int i0w = qt * QBLK + w * 32;

    // Q B-fragments: lane holds Q[i = i0w+ln][k = kc*16 + h*8 .. +7]
    short8 qf[4];
#pragma unroll
    for (int kc = 0; kc < 4; ++kc)
        qf[kc] = *(const short8*)(Qb + ((size_t)(b * LL + i0w + ln)) * 64 + kc * 16 + h * 8);

    // precomputed per-lane LDS read addresses (128B rows, &7 swizzle) — R12-proven
    int aK[4];
#pragma unroll
    for (int kc = 0; kc < 4; ++kc)
        aK[kc] = ln * 128 + ((((kc << 1) + h) ^ (ln & 7)) << 4);

    // staging: 512 lanes x 16B = one full 8KB buffer per gload16
    const int r0 = tid >> 3;                 // 0..63 (row)
    const int c0 = (tid & 7) ^ (r0 & 7);     // swizzled chunk

    const unsigned short* KbB = Kb + (size_t)b * LL * 64;
    const unsigned short* VtB = Vt + (size_t)b * 64 * LL;
    const int jbase = js * nt * KVBLK;

    f32x16 racc[2];
#pragma unroll
    for (int vg = 0; vg < 2; ++vg)
#pragma unroll
        for (int r = 0; r < 16; ++r) racc[vg][r] = 0.f;
    float ssum = 0.f;

    // prologue: stage tile 0 into buffer 0 (K rows 0..63; V rows = 64 v-channels)
    gload16(KbB + (size_t)(jbase + r0) * 64 + c0 * 8, (char*)Sh + tid * 16);
    gload16(VtB + (size_t)r0 * LL + jbase + c0 * 8, (char*)Sh + 16384 + tid * 16);

    // running prefetch sources (tile 1 onward)
    const unsigned short* pK = KbB + (size_t)(jbase + KVBLK + r0) * 64 + c0 * 8;
    const unsigned short* pV = VtB + (size_t)r0 * LL + jbase + KVBLK + c0 * 8;

#define PREF(BUFOFF)                                                            \
    do {                                                                        \
        gload16(pK, (char*)Sh + (BUFOFF) + tid * 16);                           \
        gload16(pV, (char*)Sh + 16384 + (BUFOFF) + tid * 16);                   \
        pK += KVBLK * 64; pV += KVBLK;                                          \
    } while (0)

#define COMPUTE(BUFOFF)                                                         \
    do {                                                                        \
        _Pragma("unroll")                                                       \
        for (int jt = 0; jt < 2; ++jt) {                                        \
            f32x16 sacc;                                                        \
            _Pragma("unroll")                                                   \
            for (int r = 0; r < 16; ++r) sacc[r] = 0.f;                         \
            __builtin_amdgcn_s_setprio(1);                                      \
            _Pragma("unroll")                                                   \
            for (int kc = 0; kc < 4; ++kc) {                                    \
                const short8 kf = *(const short8*)((const char*)Sh + (BUFOFF) + jt * 4096 + aK[kc]); \
                sacc = __builtin_amdgcn_mfma_f32_32x32x16_bf16(kf, qf[kc], sacc, 0, 0, 0); \
            }                                                                   \
            __builtin_amdgcn_s_setprio(0);                                      \
            _Pragma("unroll")                                                   \
            for (int r = 0; r < 16; ++r) sacc[r] = __builtin_amdgcn_exp2f(sacc[r]); \
            float s0 = 0.f;                                                     \
            _Pragma("unroll")                                                   \
            for (int r = 0; r < 16; r += 4)                                     \
                s0 += (sacc[r] + sacc[r + 1]) + (sacc[r + 2] + sacc[r + 3]);    \
            ssum += s0;                                                         \
            short8 pf[2];                                                       \
            _Pragma("unroll")                                                   \
            for (int c = 0; c < 2; ++c) {                                       \
                uint a0 = cvtpk(sacc[8 * c + 0], sacc[8 * c + 1]);              \
                uint b0 = cvtpk(sacc[8 * c + 4], sacc[8 * c + 5]);              \
                uint a1 = cvtpk(sacc[8 * c + 2], sacc[8 * c + 3]);              \
                uint b1 = cvtpk(sacc[8 * c + 6], sacc[8 * c + 7]);              \
                plswap(a0, b0);                                                 \
                plswap(a1, b1);                                                 \
                union { uint u[4]; short8 s; } P;                               \
                P.u[0] = a0; P.u[1] = a1; P.u[2] = b0; P.u[3] = b1;             \
                pf[c] = P.s;                                                    \
            }                                                                   \
            __builtin_amdgcn_s_setprio(1);                                      \
            _Pragma("unroll")                                                   \
            for (int c = 0; c < 2; ++c) {                                       \
                const int kcv = 2 * jt + c;                                     \
                _Pragma("unroll")                                               \
                for (int vg = 0; vg < 2; ++vg) {                                \
                    const short8 vf = *(const short8*)((const char*)Sh + 16384 + (BUFOFF) + vg * 4096 + aK[kcv]); \
                    racc[vg] = __builtin_amdgcn_mfma_f32_32x32x16_bf16(pf[c], vf, racc[vg], 0, 0, 0); \
                }                                                               \
            }                                                                   \
            __builtin_amdgcn_s_setprio(0);                                      \
        }                                                                       \
    } while (0)

    int t = 0;
    for (; t + 2 <= nt; t += 2) {
        __syncthreads();          // drains tile-t loads (issued a full phase ago)
        PREF(8192);               // tile t+1 -> buffer 1
        COMPUTE(0);
        __syncthreads();          // drains tile-(t+1) loads
        if (t + 2 < nt) PREF(0);  // tile t+2 -> buffer 0
        COMPUTE(8192);
    }
    if (t < nt) {                 // odd tail (buffer 0 holds last tile)
        __syncthreads();
        COMPUTE(0);
    }
#undef PREF
#undef COMPUTE

    // ---- epilogue (R8-proven mapping; 128B sectors block-internal at QBLK=256) ----
    {
        float s = ssum + __shfl_xor(ssum, 32, 64);
        if (h == 0) Sp[(size_t)(b * JS + js) * LL + i0w + ln] = s;
    }
    const size_t rBase = (size_t)(b * JS + js) * 64;
#pragma unroll
    for (int vg = 0; vg < 2; ++vg) {
        unsigned short* dst = Rp + (rBase + vg * 32 + ln) * (size_t)LL + i0w + 4 * h;
#pragma unroll
        for (int rr = 0; rr < 4; ++rr) {
            uint2v val;
            val.x = cvtpk(racc[vg][4 * rr + 0], racc[vg][4 * rr + 1]);
            val.y = cvtpk(racc[vg][4 * rr + 2], racc[vg][4 * rr + 3]);
            *(uint2v*)&dst[8 * rr] = val;
        }
    }
}

// ---------------- combine partials: 8 outputs/thread, uint4 loads ----------------
__global__ __launch_bounds__(256) void combine_kernel(
    const float* __restrict__ Sp, const unsigned short* __restrict__ Rp,
    float* __restrict__ out, int JS)
{
    size_t g8 = ((size_t)blockIdx.x * 256 + threadIdx.x) * 8;
    int l = (int)(g8 % LL);
    int v = (int)((g8 / LL) % 64);
    int b = (int)(g8 / ((size_t)64 * LL));
    float s[8], r[8];
#pragma unroll
    for (int k = 0; k < 8; ++k) { s[k] = 0.f; r[k] = 0.f; }
    for (int js = 0; js < JS; ++js) {
        const float4 sv0 = *(const float4*)&Sp[(size_t)(b * JS + js) * LL + l];
        const float4 sv1 = *(const float4*)&Sp[(size_t)(b * JS + js) * LL + l + 4];
        const uint4 rv = *(const uint4*)&Rp[((size_t)(b * JS + js) * 64 + v) * LL + l];
        s[0] += sv0.x; s[1] += sv0.y; s[2] += sv0.z; s[3] += sv0.w;
        s[4] += sv1.x; s[5] += sv1.y; s[6] += sv1.z; s[7] += sv1.w;
        r[0] += bf2f(rv.x & 0xffffu); r[1] += bf2f(rv.x >> 16);
        r[2] += bf2f(rv.y & 0xffffu); r[3] += bf2f(rv.y >> 16);
        r[4] += bf2f(rv.z & 0xffffu); r[5] += bf2f(rv.z >> 16);
        r[6] += bf2f(rv.w & 0xffffu); r[7] += bf2f(rv.w >> 16);
    }
    *(float4*)&out[g8]     = make_float4(r[0] / s[0], r[1] / s[1], r[2] / s[2], r[3] / s[3]);
    *(float4*)&out[g8 + 4] = make_float4(r[4] / s[4], r[5] / s[5], r[6] / s[6], r[7] / s[7]);
}

extern "C" void kernel_launch(void* const* d_in, const int* in_sizes, int n_in,
                              void* d_out, int out_size, void* d_ws, size_t ws_size,
                              hipStream_t stream) {
    (void)in_sizes; (void)n_in; (void)out_size;
    const float* x     = (const float*)d_in[0];
    const float* x_enc = (const float*)d_in[1];
    const float* Wq    = (const float*)d_in[2];
    const float* bq    = (const float*)d_in[3];
    const float* Wk    = (const float*)d_in[4];
    const float* bk    = (const float*)d_in[5];
    const float* Wv    = (const float*)d_in[6];
    const float* bv    = (const float*)d_in[7];
    float* out = (float*)d_out;
    char* ws = (char*)d_ws;

    const size_t nBF = (size_t)NB * LL * 64 * 2;
    unsigned short* Qb = (unsigned short*)ws;
    unsigned short* Kb = (unsigned short*)(ws + nBF);
    unsigned short* Vt = (unsigned short*)(ws + 2 * nBF);

    // JS=8: flash work is JS-invariant (R22 measurement); minimize partial traffic.
    int JS = 8;
    {
        const int cand[2] = {8, 4};
        for (int ci = 0; ci < 2; ++ci) {
            JS = cand[ci];
            size_t need = 3 * nBF + (size_t)NB * JS * LL * 4 + (size_t)NB * JS * 64 * LL * 2;
            if (need <= ws_size) break;
        }
    }
    float* Sp = (float*)(ws + 3 * nBF);
    unsigned short* Rp = (unsigned short*)(ws + 3 * nBF + (size_t)NB * JS * LL * 4);
    int nt = (LL / JS) / KVBLK;

    const int nqk = NB * LL / 64;   // 288
    proj_kernel   <<<2 * nqk, 256, 0, stream>>>(x, x_enc, Wq, bq, Wk, bk, Wv, bv, Qb, Kb, Vt, nqk);
    flash_kernel  <<<NB * JS * NQT, 512, 0, stream>>>(Qb, Kb, Vt, Sp, Rp, JS, nt);
    combine_kernel<<<(NB * 64 * LL) / 2048, 256, 0, stream>>>(Sp, Rp, out, JS);
}

// Round 24
// 95.778 us; speedup vs baseline: 1.0227x; 1.0227x over previous
//
#include <hip/hip_runtime.h>
#include <hip/hip_bf16.h>
#include <math.h>

#define NB   2
#define CIN  64
#define CENC 96
#define DK   64
#define DV   64
#define LL   9216
#define QBLK 256
#define KVBLK 64
#define NQT  (LL/QBLK)          // 36
#define LOG2E 1.44269504088896340736f

typedef __attribute__((ext_vector_type(8)))  short short8;
typedef __attribute__((ext_vector_type(16))) float f32x16;
typedef __attribute__((ext_vector_type(2)))  unsigned int uint2v;
typedef unsigned int uint;

__device__ inline void gload16(const void* g, void* l) {
    __builtin_amdgcn_global_load_lds(
        (const __attribute__((address_space(1))) unsigned int*)g,
        (__attribute__((address_space(3))) unsigned int*)l, 16, 0, 0);
}

__device__ inline unsigned short f2bf(float f) {
    union { float f; uint u; } v; v.f = f;
    uint r = (v.u + 0x7FFFu + ((v.u >> 16) & 1u)) >> 16;
    return (unsigned short)r;
}

__device__ inline float bf2f(uint u) {
    union { uint u; float f; } c; c.u = u << 16; return c.f;
}

// single-instruction packed f32->bf16 (RNE)
__device__ inline uint cvtpk(float lo, float hi) {
    uint r;
    asm("v_cvt_pk_bf16_f32 %0, %1, %2" : "=v"(r) : "v"(lo), "v"(hi));
    return r;
}

// exchange a[32:63] <-> b[0:31]
__device__ inline void plswap(uint& a, uint& b) {
#if __has_builtin(__builtin_amdgcn_permlane32_swap)
    uint2v r = __builtin_amdgcn_permlane32_swap(a, b, false, false);
    a = r.x; b = r.y;
#else
    const int lane = threadIdx.x & 63;
    uint t = (lane < 32) ? b : a;
    t = __shfl_xor(t, 32, 64);
    uint an = (lane < 32) ? a : t;
    uint bn = (lane < 32) ? t : b;
    a = an; b = bn;
#endif
}

// ---------------- fused projections (float4 x-loads) ----------------
__global__ __launch_bounds__(256) void proj_kernel(
    const float* __restrict__ x, const float* __restrict__ x_enc,
    const float* __restrict__ Wq, const float* __restrict__ bq,
    const float* __restrict__ Wk, const float* __restrict__ bk,
    const float* __restrict__ Wv, const float* __restrict__ bv,
    unsigned short* __restrict__ Qb, unsigned short* __restrict__ Kb,
    unsigned short* __restrict__ Vt, int nqk)
{
    __shared__ float sh[2 * CENC * 64];   // 48KB
    const int tid = threadIdx.x;

    if ((int)blockIdx.x < nqk) {
        float* Wt0 = sh;
        float* Wt1 = sh + CENC * 64;
        for (int idx = tid; idx < DK * CENC; idx += 256) {
            int k = idx / CENC, c = idx - k * CENC;
            Wt0[c * 64 + (k ^ (c & 31))] = Wq[idx];
            Wt1[c * 64 + (k ^ (c & 31))] = Wk[idx];
        }
        __syncthreads();

        const int w    = __builtin_amdgcn_readfirstlane(tid >> 6);
        const int lane = tid & 63;
        const int gw   = blockIdx.x * 4 + w;
        const int p0g  = gw * 16;
        const int b    = p0g / LL;
        const int p0   = p0g - b * LL;

        float qa[16], ka[16];
        const float bqv = bq[lane], bkv = bk[lane];
#pragma unroll
        for (int p = 0; p < 16; ++p) { qa[p] = bqv; ka[p] = bkv; }

        const float* xp = x_enc + (size_t)b * CENC * LL + p0;
#pragma unroll 4
        for (int c = 0; c < CENC; ++c) {
            const float wq = Wt0[c * 64 + (lane ^ (c & 31))];
            const float wk = Wt1[c * 64 + (lane ^ (c & 31))];
            const float4* xc4 = (const float4*)(xp + (size_t)c * LL);
#pragma unroll
            for (int p4 = 0; p4 < 4; ++p4) {
                const float4 xv = xc4[p4];
                qa[4 * p4 + 0] = fmaf(wq, xv.x, qa[4 * p4 + 0]);
                qa[4 * p4 + 1] = fmaf(wq, xv.y, qa[4 * p4 + 1]);
                qa[4 * p4 + 2] = fmaf(wq, xv.z, qa[4 * p4 + 2]);
                qa[4 * p4 + 3] = fmaf(wq, xv.w, qa[4 * p4 + 3]);
                ka[4 * p4 + 0] = fmaf(wk, xv.x, ka[4 * p4 + 0]);
                ka[4 * p4 + 1] = fmaf(wk, xv.y, ka[4 * p4 + 1]);
                ka[4 * p4 + 2] = fmaf(wk, xv.z, ka[4 * p4 + 2]);
                ka[4 * p4 + 3] = fmaf(wk, xv.w, ka[4 * p4 + 3]);
            }
        }

        unsigned short* qrow = Qb + (size_t)(b * LL + p0) * 64 + lane;
        unsigned short* krow = Kb + (size_t)(b * LL + p0) * 64 + lane;
#pragma unroll
        for (int p = 0; p < 16; ++p) {
            float sq = qa[p] * qa[p];
            float sk = ka[p] * ka[p];
#pragma unroll
            for (int m = 1; m < 64; m <<= 1) {
                sq += __shfl_xor(sq, m, 64);
                sk += __shfl_xor(sk, m, 64);
            }
            qrow[(size_t)p * 64] = f2bf(qa[p] * (LOG2E / fmaxf(sqrtf(sq), 1e-6f)));
            krow[(size_t)p * 64] = f2bf(ka[p] * (1.f / fmaxf(sqrtf(sk), 1e-6f)));
        }
    } else {
        float* Wt = sh;                                        // 16KB
        unsigned short* Vsh = (unsigned short*)(sh + CIN * 64); // 8KB
        for (int idx = tid; idx < DV * CIN; idx += 256) {
            int v = idx / CIN, c = idx - v * CIN;
            Wt[c * 64 + (v ^ (c & 31))] = Wv[idx];
        }
        __syncthreads();

        const int w    = __builtin_amdgcn_readfirstlane(tid >> 6);
        const int lane = tid & 63;
        const int l0g  = ((int)blockIdx.x - nqk) * 64;
        const int b    = l0g / LL;
        const int l0   = l0g - b * LL;
        const int p0   = w * 16;

        float va[16];
        const float bvv = bv[lane];
#pragma unroll
        for (int p = 0; p < 16; ++p) va[p] = bvv;

        const float* xp = x + (size_t)b * CIN * LL + l0 + p0;
#pragma unroll 4
        for (int c = 0; c < CIN; ++c) {
            const float wv = Wt[c * 64 + (lane ^ (c & 31))];
            const float4* xc4 = (const float4*)(xp + (size_t)c * LL);
#pragma unroll
            for (int p4 = 0; p4 < 4; ++p4) {
                const float4 xv = xc4[p4];
                va[4 * p4 + 0] = fmaf(wv, xv.x, va[4 * p4 + 0]);
                va[4 * p4 + 1] = fmaf(wv, xv.y, va[4 * p4 + 1]);
                va[4 * p4 + 2] = fmaf(wv, xv.z, va[4 * p4 + 2]);
                va[4 * p4 + 3] = fmaf(wv, xv.w, va[4 * p4 + 3]);
            }
        }
#pragma unroll
        for (int p = 0; p < 16; ++p) Vsh[(p0 + p) * 64 + lane] = f2bf(va[p]);
        __syncthreads();

        const int v = tid & 63, w2 = tid >> 6;
        uint pk[8];
#pragma unroll
        for (int j = 0; j < 8; ++j)
            pk[j] = (uint)Vsh[(w2 * 16 + 2 * j) * 64 + v] |
                    ((uint)Vsh[(w2 * 16 + 2 * j + 1) * 64 + v] << 16);
        uint4* dst = (uint4*)(Vt + (size_t)b * 64 * LL + (size_t)v * LL + l0 + w2 * 16);
        dst[0] = make_uint4(pk[0], pk[1], pk[2], pk[3]);
        dst[1] = make_uint4(pk[4], pk[5], pk[6], pk[7]);
    }
}

// ---------------- MFMA flash attention: 8 waves x 32q, 4 waves/SIMD (R17-proven) ----------------
__global__ __launch_bounds__(512, 4) void flash_kernel(
    const unsigned short* __restrict__ Qb,
    const unsigned short* __restrict__ Kb,
    const unsigned short* __restrict__ Vt,
    float* __restrict__ Sp, unsigned short* __restrict__ Rp,
    int JS, int nt)
{
    // LDS bytes: K buf0 @0, K buf1 @8192, V buf0 @16384, V buf1 @24576
    __shared__ unsigned short Sh[16384];

    // XCD-aware bijective swizzle (grid divisible by 8)
    const int bid0  = blockIdx.x;
    const int chunk = gridDim.x >> 3;
    const int bid   = (bid0 & 7) * chunk + (bid0 >> 3);

    const int qt  = bid % NQT;
    const int js  = (bid / NQT) % JS;
    const int b   = bid / (NQT * JS);
    const int tid = threadIdx.x;
    const int w = tid >> 6, lane = tid & 63;
    const int ln = lane & 31, h = lane >> 5;
    const int i0w = qt * QBLK + w * 32;

    // Q B-fragments: lane holds Q[i = i0w+ln][k = kc*16 + h*8 .. +7]
    short8 qf[4];
#pragma unroll
    for (int kc = 0; kc < 4; ++kc)
        qf[kc] = *(const short8*)(Qb + ((size_t)(b * LL + i0w + ln)) * 64 + kc * 16 + h * 8);

    // precomputed per-lane LDS read addresses (128B rows, &7 swizzle) — R12-proven
    int aK[4];
#pragma unroll
    for (int kc = 0; kc < 4; ++kc)
        aK[kc] = ln * 128 + ((((kc << 1) + h) ^ (ln & 7)) << 4);

    // staging: 512 lanes x 16B = one full 8KB buffer per gload16
    const int r0 = tid >> 3;                 // 0..63 (row)
    const int c0 = (tid & 7) ^ (r0 & 7);     // swizzled chunk

    const unsigned short* KbB = Kb + (size_t)b * LL * 64;
    const unsigned short* VtB = Vt + (size_t)b * 64 * LL;
    const int jbase = js * nt * KVBLK;

    f32x16 racc[2];
#pragma unroll
    for (int vg = 0; vg < 2; ++vg)
#pragma unroll
        for (int r = 0; r < 16; ++r) racc[vg][r] = 0.f;
    float ssum = 0.f;

    // prologue: stage tile 0 into buffer 0 (K rows 0..63; V rows = 64 v-channels)
    gload16(KbB + (size_t)(jbase + r0) * 64 + c0 * 8, (char*)Sh + tid * 16);
    gload16(VtB + (size_t)r0 * LL + jbase + c0 * 8, (char*)Sh + 16384 + tid * 16);

    // running prefetch sources (tile 1 onward)
    const unsigned short* pK = KbB + (size_t)(jbase + KVBLK + r0) * 64 + c0 * 8;
    const unsigned short* pV = VtB + (size_t)r0 * LL + jbase + KVBLK + c0 * 8;

#define PREF(BUFOFF)                                                            \
    do {                                                                        \
        gload16(pK, (char*)Sh + (BUFOFF) + tid * 16);                           \
        gload16(pV, (char*)Sh + 16384 + (BUFOFF) + tid * 16);                   \
        pK += KVBLK * 64; pV += KVBLK;                                          \
    } while (0)

#define COMPUTE(BUFOFF)                                                         \
    do {                                                                        \
        _Pragma("unroll")                                                       \
        for (int jt = 0; jt < 2; ++jt) {                                        \
            f32x16 sacc;                                                        \
            _Pragma("unroll")                                                   \
            for (int r = 0; r < 16; ++r) sacc[r] = 0.f;                         \
            __builtin_amdgcn_s_setprio(1);                                      \
            _Pragma("unroll")                                                   \
            for (int kc = 0; kc < 4; ++kc) {                                    \
                const short8 kf = *(const short8*)((const char*)Sh + (BUFOFF) + jt * 4096 + aK[kc]); \
                sacc = __builtin_amdgcn_mfma_f32_32x32x16_bf16(kf, qf[kc], sacc, 0, 0, 0); \
            }                                                                   \
            __builtin_amdgcn_s_setprio(0);                                      \
            _Pragma("unroll")                                                   \
            for (int r = 0; r < 16; ++r) sacc[r] = __builtin_amdgcn_exp2f(sacc[r]); \
            float s0 = 0.f;                                                     \
            _Pragma("unroll")                                                   \
            for (int r = 0; r < 16; r += 4)                                     \
                s0 += (sacc[r] + sacc[r + 1]) + (sacc[r + 2] + sacc[r + 3]);    \
            ssum += s0;                                                         \
            short8 pf[2];                                                       \
            _Pragma("unroll")                                                   \
            for (int c = 0; c < 2; ++c) {                                       \
                uint a0 = cvtpk(sacc[8 * c + 0], sacc[8 * c + 1]);              \
                uint b0 = cvtpk(sacc[8 * c + 4], sacc[8 * c + 5]);              \
                uint a1 = cvtpk(sacc[8 * c + 2], sacc[8 * c + 3]);              \
                uint b1 = cvtpk(sacc[8 * c + 6], sacc[8 * c + 7]);              \
                plswap(a0, b0);                                                 \
                plswap(a1, b1);                                                 \
                union { uint u[4]; short8 s; } P;                               \
                P.u[0] = a0; P.u[1] = a1; P.u[2] = b0; P.u[3] = b1;             \
                pf[c] = P.s;                                                    \
            }                                                                   \
            __builtin_amdgcn_s_setprio(1);                                      \
            _Pragma("unroll")                                                   \
            for (int c = 0; c < 2; ++c) {                                       \
                const int kcv = 2 * jt + c;                                     \
                _Pragma("unroll")                                               \
                for (int vg = 0; vg < 2; ++vg) {                                \
                    const short8 vf = *(const short8*)((const char*)Sh + 16384 + (BUFOFF) + vg * 4096 + aK[kcv]); \
                    racc[vg] = __builtin_amdgcn_mfma_f32_32x32x16_bf16(pf[c], vf, racc[vg], 0, 0, 0); \
                }                                                               \
            }                                                                   \
            __builtin_amdgcn_s_setprio(0);                                      \
        }                                                                       \
    } while (0)

    int t = 0;
    for (; t + 2 <= nt; t += 2) {
        __syncthreads();          // drains tile-t loads (issued a full phase ago)
        PREF(8192);               // tile t+1 -> buffer 1
        COMPUTE(0);
        __syncthreads();          // drains tile-(t+1) loads
        if (t + 2 < nt) PREF(0);  // tile t+2 -> buffer 0
        COMPUTE(8192);
    }
    if (t < nt) {                 // odd tail (buffer 0 holds last tile)
        __syncthreads();
        COMPUTE(0);
    }
#undef PREF
#undef COMPUTE

    // ---- epilogue (R8-proven mapping; 128B sectors block-internal at QBLK=256) ----
    {
        float s = ssum + __shfl_xor(ssum, 32, 64);
        if (h == 0) Sp[(size_t)(b * JS + js) * LL + i0w + ln] = s;
    }
    const size_t rBase = (size_t)(b * JS + js) * 64;
#pragma unroll
    for (int vg = 0; vg < 2; ++vg) {
        unsigned short* dst = Rp + (rBase + vg * 32 + ln) * (size_t)LL + i0w + 4 * h;
#pragma unroll
        for (int rr = 0; rr < 4; ++rr) {
            uint2v val;
            val.x = cvtpk(racc[vg][4 * rr + 0], racc[vg][4 * rr + 1]);
            val.y = cvtpk(racc[vg][4 * rr + 2], racc[vg][4 * rr + 3]);
            *(uint2v*)&dst[8 * rr] = val;
        }
    }
}

// ---------------- combine partials: 8 outputs/thread, uint4 loads ----------------
__global__ __launch_bounds__(256) void combine_kernel(
    const float* __restrict__ Sp, const unsigned short* __restrict__ Rp,
    float* __restrict__ out, int JS)
{
    size_t g8 = ((size_t)blockIdx.x * 256 + threadIdx.x) * 8;
    int l = (int)(g8 % LL);
    int v = (int)((g8 / LL) % 64);
    int b = (int)(g8 / ((size_t)64 * LL));
    float s[8], r[8];
#pragma unroll
    for (int k = 0; k < 8; ++k) { s[k] = 0.f; r[k] = 0.f; }
    for (int js = 0; js < JS; ++js) {
        const float4 sv0 = *(const float4*)&Sp[(size_t)(b * JS + js) * LL + l];
        const float4 sv1 = *(const float4*)&Sp[(size_t)(b * JS + js) * LL + l + 4];
        const uint4 rv = *(const uint4*)&Rp[((size_t)(b * JS + js) * 64 + v) * LL + l];
        s[0] += sv0.x; s[1] += sv0.y; s[2] += sv0.z; s[3] += sv0.w;
        s[4] += sv1.x; s[5] += sv1.y; s[6] += sv1.z; s[7] += sv1.w;
        r[0] += bf2f(rv.x & 0xffffu); r[1] += bf2f(rv.x >> 16);
        r[2] += bf2f(rv.y & 0xffffu); r[3] += bf2f(rv.y >> 16);
        r[4] += bf2f(rv.z & 0xffffu); r[5] += bf2f(rv.z >> 16);
        r[6] += bf2f(rv.w & 0xffffu); r[7] += bf2f(rv.w >> 16);
    }
    *(float4*)&out[g8]     = make_float4(r[0] / s[0], r[1] / s[1], r[2] / s[2], r[3] / s[3]);
    *(float4*)&out[g8 + 4] = make_float4(r[4] / s[4], r[5] / s[5], r[6] / s[6], r[7] / s[7]);
}

extern "C" void kernel_launch(void* const* d_in, const int* in_sizes, int n_in,
                              void* d_out, int out_size, void* d_ws, size_t ws_size,
                              hipStream_t stream) {
    (void)in_sizes; (void)n_in; (void)out_size;
    const float* x     = (const float*)d_in[0];
    const float* x_enc = (const float*)d_in[1];
    const float* Wq    = (const float*)d_in[2];
    const float* bq    = (const float*)d_in[3];
    const float* Wk    = (const float*)d_in[4];
    const float* bk    = (const float*)d_in[5];
    const float* Wv    = (const float*)d_in[6];
    const float* bv    = (const float*)d_in[7];
    float* out = (float*)d_out;
    char* ws = (char*)d_ws;

    const size_t nBF = (size_t)NB * LL * 64 * 2;
    unsigned short* Qb = (unsigned short*)ws;
    unsigned short* Kb = (unsigned short*)(ws + nBF);
    unsigned short* Vt = (unsigned short*)(ws + 2 * nBF);

    // JS=12 (R22-measured optimum): grid 864 keeps machine full with minimal
    // partial traffic; JS=8's 576-block grid leaves a 64-block tail round (R23).
    int JS = 12;
    {
        const int cand[2] = {12, 8};
        for (int ci = 0; ci < 2; ++ci) {
            JS = cand[ci];
            size_t need = 3 * nBF + (size_t)NB * JS * LL * 4 + (size_t)NB * JS * 64 * LL * 2;
            if (need <= ws_size) break;
        }
    }
    float* Sp = (float*)(ws + 3 * nBF);
    unsigned short* Rp = (unsigned short*)(ws + 3 * nBF + (size_t)NB * JS * LL * 4);
    int nt = (LL / JS) / KVBLK;

    const int nqk = NB * LL / 64;   // 288
    proj_kernel   <<<2 * nqk, 256, 0, stream>>>(x, x_enc, Wq, bq, Wk, bk, Wv, bv, Qb, Kb, Vt, nqk);
    flash_kernel  <<<NB * JS * NQT, 512, 0, stream>>>(Qb, Kb, Vt, Sp, Rp, JS, nt);
    combine_kernel<<<(NB * 64 * LL) / 2048, 256, 0, stream>>>(Sp, Rp, out, JS);
}